// Round 4
// baseline (565.038 us; speedup 1.0000x reference)
//
#include <hip/hip_runtime.h>
#include <hip/hip_bf16.h>

// LengthRegulator on MI355X — R4: conv MFMA kernels unchanged (verified,
// absmax 0.0); small kernels vectorized/fused:
//   prep_x/ln_split -> half8 16B stores; dur_scan -> shuffle scan;
//   gather -> float4 writes, h-tiled grid, incremental searchsorted.

#define BB 32
#define HHD 384
#define TTOT 1024
#define MAXL 4096

typedef _Float16 half8 __attribute__((ext_vector_type(8)));
typedef float floatx4 __attribute__((ext_vector_type(4)));

// ---------------------------------------------------------------------------
// prep_w: W[h][hi][k] fp32 -> Wq[s] f16, layout e = ((c*3+k)*384 + h)*32 + d,
// where c = hi/32, d = hi%32. Split: hi = f16(w), lo = f16((w-hi)*2048).
__global__ void prep_w_kernel(const float* __restrict__ W1,
                              const float* __restrict__ W2,
                              _Float16* __restrict__ q1h, _Float16* __restrict__ q1l,
                              _Float16* __restrict__ q2h, _Float16* __restrict__ q2l) {
    const int e = blockIdx.x * 256 + threadIdx.x;     // < 442368
    const float* W = blockIdx.y ? W2 : W1;
    _Float16* oh = blockIdx.y ? q2h : q1h;
    _Float16* ol = blockIdx.y ? q2l : q1l;
    const int d  = e & 31;
    const int m  = (e >> 5) % 384;
    const int ck = e / (32 * 384);
    const int c  = ck / 3, k = ck - 3 * c;
    const float w = W[(size_t)m * 1152 + (size_t)(32 * c + d) * 3 + k];
    const _Float16 hi = (_Float16)w;
    oh[e] = hi;
    ol[e] = (_Float16)((w - (float)hi) * 2048.0f);
}

// ---------------------------------------------------------------------------
// prep_x: x[b][h][t] fp32 -> Xt1/Xt2 f16 [b][t][384], half8 vector stores.
// Tile 64h x 64t. LDS stage [h][t] stride 65 (stage 2-way, read 2-way banks).
__global__ void prep_x_kernel(const float* __restrict__ X,
                              _Float16* __restrict__ o1,
                              _Float16* __restrict__ o2) {
    __shared__ float Ls[64][65];
    const int h0 = blockIdx.x * 64;
    const int t0 = blockIdx.y * 64;
    const int b  = blockIdx.z;
    const int tid = threadIdx.x;
    const int tl = tid & 63, w = tid >> 6;
    const float* Xb = X + (size_t)b * HHD * TTOT;
#pragma unroll
    for (int i = 0; i < 16; ++i) {
        const int h = i * 4 + w;
        Ls[h][tl] = Xb[(size_t)(h0 + h) * TTOT + t0 + tl];
    }
    __syncthreads();
    const int g = tl >> 3, q = tl & 7;
#pragma unroll
    for (int j = 0; j < 2; ++j) {
        const int tloc = w * 16 + j * 8 + g;
        half8 vh, vl;
#pragma unroll
        for (int i = 0; i < 8; ++i) {
            const float f = Ls[8 * q + i][tloc];
            const _Float16 a = (_Float16)f;
            vh[i] = a;
            vl[i] = (_Float16)((f - (float)a) * 2048.0f);
        }
        const size_t o = ((size_t)b * TTOT + t0 + tloc) * HHD + h0 + 8 * q;
        *(half8*)&o1[o] = vh;
        *(half8*)&o2[o] = vl;
    }
}

// ---------------------------------------------------------------------------
// conv_mfma: C[96 m][128 t] per block. K = 12 chunks x (3 k-steps of 32).
// A = Wq (pre-split f16), B = Xt/H1t [b][t][384] splits (halo via t-shift).
// acc_hh += a1*b1 ; acc_x += a1*b2' + a2'*b1 ; out = acc_hh + acc_x/2048 + bias.
// 4 waves, wave tile 48x64. LDS 66,880 B -> 2 blocks/CU.  [UNCHANGED]
__launch_bounds__(256, 2)
__global__ void conv_mfma_kernel(const _Float16* __restrict__ Bh,  // [b][t][384]
                                 const _Float16* __restrict__ Bl,
                                 const _Float16* __restrict__ Ah,  // Wq hi
                                 const _Float16* __restrict__ Al,  // Wq lo
                                 const float* __restrict__ bias,
                                 float* __restrict__ Out) {        // h_raw [b][t][384]
    __shared__ __align__(16) _Float16 sm[33440];  // W: [2][3][96][40] @0, X: [2][130][40] @23040
    const int tid  = threadIdx.x;
    const int lane = tid & 63, wid = tid >> 6;
    const int wm = wid >> 1, wn = wid & 1;
    const int l15 = lane & 15, g4 = lane >> 4;
    const int h0 = blockIdx.x * 96;
    const int t0 = blockIdx.y * 128;
    const int b  = blockIdx.z;

    floatx4 ahh[3][4], axx[3][4];
#pragma unroll
    for (int mt = 0; mt < 3; ++mt)
#pragma unroll
        for (int nt = 0; nt < 4; ++nt) {
            ahh[mt][nt] = (floatx4){0.f, 0.f, 0.f, 0.f};
            axx[mt][nt] = (floatx4){0.f, 0.f, 0.f, 0.f};
        }

    const size_t xbase = (size_t)b * TTOT * HHD;

    for (int ch = 0; ch < 12; ++ch) {
        __syncthreads();
#pragma unroll
        for (int it = 0; it < 9; ++it) {
            const int e  = tid + it * 256;
            const int s  = e / 1152;
            const int r1 = e - s * 1152;
            const int k  = r1 / 384;
            const int q  = r1 - k * 384;
            const int m  = q >> 2, c8 = (q & 3) << 3;
            const _Float16* src = (s ? Al : Ah) +
                ((size_t)((ch * 3 + k) * 384 + h0 + m) << 5) + c8;
            const uint4 v = *(const uint4*)src;
            *(uint4*)&sm[((s * 3 + k) * 96 + m) * 40 + c8] = v;
        }
#pragma unroll
        for (int it = 0; it < 5; ++it) {
            const int e = tid + it * 256;
            if (e < 1040) {
                const int s  = e / 520;
                const int r1 = e - s * 520;
                const int j  = r1 >> 2, q = r1 & 3;
                const int gt = t0 - 1 + j;
                uint4 v = make_uint4(0u, 0u, 0u, 0u);
                if (gt >= 0 && gt < TTOT) {
                    const _Float16* src = (s ? Bl : Bh) + xbase +
                        (size_t)gt * HHD + ch * 32 + (q << 3);
                    v = *(const uint4*)src;
                }
                *(uint4*)&sm[23040 + (s * 130 + j) * 40 + (q << 3)] = v;
            }
        }
        __syncthreads();

#pragma unroll
        for (int k = 0; k < 3; ++k) {
            half8 ah[3], al[3], bh[4], bl[4];
#pragma unroll
            for (int mt = 0; mt < 3; ++mt) {
                const int m = wm * 48 + mt * 16 + l15;
                ah[mt] = *(const half8*)&sm[((0 + k) * 96 + m) * 40 + g4 * 8];
                al[mt] = *(const half8*)&sm[((3 + k) * 96 + m) * 40 + g4 * 8];
            }
#pragma unroll
            for (int nt = 0; nt < 4; ++nt) {
                const int j = wn * 64 + nt * 16 + l15 + k;
                bh[nt] = *(const half8*)&sm[23040 + (0   + j) * 40 + g4 * 8];
                bl[nt] = *(const half8*)&sm[23040 + (130 + j) * 40 + g4 * 8];
            }
#pragma unroll
            for (int mt = 0; mt < 3; ++mt)
#pragma unroll
                for (int nt = 0; nt < 4; ++nt) {
                    ahh[mt][nt] = __builtin_amdgcn_mfma_f32_16x16x32_f16(
                        ah[mt], bh[nt], ahh[mt][nt], 0, 0, 0);
                    axx[mt][nt] = __builtin_amdgcn_mfma_f32_16x16x32_f16(
                        ah[mt], bl[nt], axx[mt][nt], 0, 0, 0);
                    axx[mt][nt] = __builtin_amdgcn_mfma_f32_16x16x32_f16(
                        al[mt], bh[nt], axx[mt][nt], 0, 0, 0);
                }
        }
    }

    __syncthreads();
    float* Lt = (float*)sm;  // [128][100]
#pragma unroll
    for (int mt = 0; mt < 3; ++mt)
#pragma unroll
        for (int nt = 0; nt < 4; ++nt) {
            const int row = wn * 64 + nt * 16 + l15;     // t within tile
            const int col = wm * 48 + mt * 16 + g4 * 4;  // h within tile
            float4 v;
            v.x = ahh[mt][nt][0] + axx[mt][nt][0] * (1.0f / 2048.0f);
            v.y = ahh[mt][nt][1] + axx[mt][nt][1] * (1.0f / 2048.0f);
            v.z = ahh[mt][nt][2] + axx[mt][nt][2] * (1.0f / 2048.0f);
            v.w = ahh[mt][nt][3] + axx[mt][nt][3] * (1.0f / 2048.0f);
            *(float4*)&Lt[row * 100 + col] = v;
        }
    __syncthreads();
    const size_t obase = ((size_t)b * TTOT + t0) * HHD + h0;
#pragma unroll
    for (int i = 0; i < 12; ++i) {
        const int e = tid + i * 256;
        const int row = e / 24, c4 = (e - row * 24) * 4;
        float4 v = *(const float4*)&Lt[row * 100 + c4];
        const float4 bv = *(const float4*)&bias[h0 + c4];
        v.x += bv.x; v.y += bv.y; v.z += bv.z; v.w += bv.w;
        *(float4*)&Out[obase + (size_t)row * HHD + c4] = v;
    }
}

// ---------------------------------------------------------------------------
// ln_split: LayerNorm(ch)+ReLU on h_raw [row][384], emit f16 splits.
// 48 active lanes/row, float4 reads, half8 stores.
__global__ void ln_split_kernel(const float* __restrict__ hraw,
                                const float* __restrict__ g,
                                const float* __restrict__ be,
                                _Float16* __restrict__ o1,
                                _Float16* __restrict__ o2) {
    const int row = blockIdx.x * 4 + (threadIdx.x >> 6);
    const int l   = threadIdx.x & 63;
    const float* src = hraw + (size_t)row * HHD;
    float4 va = {0, 0, 0, 0}, vb = {0, 0, 0, 0};
    if (l < 48) {
        va = *(const float4*)&src[8 * l];
        vb = *(const float4*)&src[8 * l + 4];
    }
    float s  = va.x + va.y + va.z + va.w + vb.x + vb.y + vb.z + vb.w;
    float ss = va.x * va.x + va.y * va.y + va.z * va.z + va.w * va.w +
               vb.x * vb.x + vb.y * vb.y + vb.z * vb.z + vb.w * vb.w;
#pragma unroll
    for (int m = 32; m >= 1; m >>= 1) {
        s  += __shfl_xor(s, m, 64);
        ss += __shfl_xor(ss, m, 64);
    }
    const float mean = s * (1.f / HHD);
    const float inv  = rsqrtf(ss * (1.f / HHD) - mean * mean + 1e-5f);
    if (l < 48) {
        const float4 ga = *(const float4*)&g[8 * l];
        const float4 gb = *(const float4*)&g[8 * l + 4];
        const float4 ba = *(const float4*)&be[8 * l];
        const float4 bb = *(const float4*)&be[8 * l + 4];
        float y[8];
        y[0] = (va.x - mean) * inv * ga.x + ba.x;
        y[1] = (va.y - mean) * inv * ga.y + ba.y;
        y[2] = (va.z - mean) * inv * ga.z + ba.z;
        y[3] = (va.w - mean) * inv * ga.w + ba.w;
        y[4] = (vb.x - mean) * inv * gb.x + bb.x;
        y[5] = (vb.y - mean) * inv * gb.y + bb.y;
        y[6] = (vb.z - mean) * inv * gb.z + bb.z;
        y[7] = (vb.w - mean) * inv * gb.w + bb.w;
        half8 vh, vl;
#pragma unroll
        for (int i = 0; i < 8; ++i) {
            const float r = fmaxf(y[i], 0.f);
            const _Float16 a = (_Float16)r;
            vh[i] = a;
            vl[i] = (_Float16)((r - (float)a) * 2048.0f);
        }
        const size_t o = (size_t)row * HHD + 8 * l;
        *(half8*)&o1[o] = vh;
        *(half8*)&o2[o] = vl;
    }
}

// ---------------------------------------------------------------------------
// ln_proj: LayerNorm + ReLU + dot(Wl) + bl + ReLU -> z[row].
__global__ void ln_proj_kernel(const float* __restrict__ hraw,
                               const float* __restrict__ g,
                               const float* __restrict__ be,
                               const float* __restrict__ Wl,
                               const float* __restrict__ blp,
                               float* __restrict__ zb) {
    const int row = blockIdx.x * 4 + (threadIdx.x >> 6);
    const int l   = threadIdx.x & 63;
    const float* src = hraw + (size_t)row * HHD;
    float4 va = {0, 0, 0, 0}, vb = {0, 0, 0, 0};
    if (l < 48) {
        va = *(const float4*)&src[8 * l];
        vb = *(const float4*)&src[8 * l + 4];
    }
    float s  = va.x + va.y + va.z + va.w + vb.x + vb.y + vb.z + vb.w;
    float ss = va.x * va.x + va.y * va.y + va.z * va.z + va.w * va.w +
               vb.x * vb.x + vb.y * vb.y + vb.z * vb.z + vb.w * vb.w;
#pragma unroll
    for (int m = 32; m >= 1; m >>= 1) {
        s  += __shfl_xor(s, m, 64);
        ss += __shfl_xor(ss, m, 64);
    }
    const float mean = s * (1.f / HHD);
    const float inv  = rsqrtf(ss * (1.f / HHD) - mean * mean + 1e-5f);
    float zs = 0.f;
    if (l < 48) {
        const float4 ga = *(const float4*)&g[8 * l];
        const float4 gb = *(const float4*)&g[8 * l + 4];
        const float4 ba = *(const float4*)&be[8 * l];
        const float4 bb = *(const float4*)&be[8 * l + 4];
        const float4 wa = *(const float4*)&Wl[8 * l];
        const float4 wb = *(const float4*)&Wl[8 * l + 4];
        zs += fmaxf((va.x - mean) * inv * ga.x + ba.x, 0.f) * wa.x;
        zs += fmaxf((va.y - mean) * inv * ga.y + ba.y, 0.f) * wa.y;
        zs += fmaxf((va.z - mean) * inv * ga.z + ba.z, 0.f) * wa.z;
        zs += fmaxf((va.w - mean) * inv * ga.w + ba.w, 0.f) * wa.w;
        zs += fmaxf((vb.x - mean) * inv * gb.x + bb.x, 0.f) * wb.x;
        zs += fmaxf((vb.y - mean) * inv * gb.y + bb.y, 0.f) * wb.y;
        zs += fmaxf((vb.z - mean) * inv * gb.z + bb.z, 0.f) * wb.z;
        zs += fmaxf((vb.w - mean) * inv * gb.w + bb.w, 0.f) * wb.w;
    }
#pragma unroll
    for (int m = 32; m >= 1; m >>= 1) zs += __shfl_xor(zs, m, 64);
    if (l == 0) zb[row] = fmaxf(zs + blp[0], 0.f);
}

// ---------------------------------------------------------------------------
// dur_scan: durations=floor(exp(z)), inclusive scan. 1 block/b, 256 thr x 4.
__global__ void dur_scan_kernel(const float* __restrict__ z,
                                float* __restrict__ durOut,
                                int* __restrict__ cum) {
    __shared__ int wsum[4];
    const int b = blockIdx.x;
    const int tid = threadIdx.x;
    const int l = tid & 63, w = tid >> 6;
    const float4 zv = *(const float4*)&z[b * TTOT + tid * 4];
    int d0 = (int)floorf(expf(zv.x));
    int d1 = (int)floorf(expf(zv.y));
    int d2 = (int)floorf(expf(zv.z));
    int d3 = (int)floorf(expf(zv.w));
    *(float4*)&durOut[b * TTOT + tid * 4] =
        make_float4((float)d0, (float)d1, (float)d2, (float)d3);
    const int s4 = d0 + d1 + d2 + d3;
    int sc = s4;
#pragma unroll
    for (int off = 1; off <= 32; off <<= 1) {
        const int v = __shfl_up(sc, off, 64);
        if (l >= off) sc += v;
    }
    if (l == 63) wsum[w] = sc;
    __syncthreads();
    int base = 0;
#pragma unroll
    for (int j = 0; j < 4; ++j)
        if (j < w) base += wsum[j];
    const int ex = base + sc - s4;
    int4 c;
    c.x = ex + d0; c.y = c.x + d1; c.z = c.y + d2; c.w = c.z + d3;
    *(int4*)&cum[b * TTOT + tid * 4] = c;
}

// ---------------------------------------------------------------------------
// gather: searchsorted + masked gather, float4 writes.
// Grid (4 pos-tiles, 8 h-tiles, B). Uses durations>=1 => cum strictly increasing.
__global__ void gather_kernel(const float* __restrict__ X,
                              const int* __restrict__ cum,
                              float* __restrict__ aligned) {
    __shared__ int cs[TTOT];
    const int pt = blockIdx.x, ht = blockIdx.y, b = blockIdx.z;
    const int tid = threadIdx.x;
#pragma unroll
    for (int i = 0; i < 4; ++i) cs[tid + 256 * i] = cum[b * TTOT + tid + 256 * i];
    __syncthreads();

    const int total = cs[TTOT - 1];
    const int pos0 = pt * 1024 + tid * 4;
    int lo = 0, hi = TTOT;
    while (lo < hi) {
        const int mid = (lo + hi) >> 1;
        if (cs[mid] <= pos0) lo = mid + 1; else hi = mid;
    }
    int id0 = lo;
    int id1 = (id0 < TTOT && cs[id0] <= pos0 + 1) ? id0 + 1 : id0;
    int id2 = (id1 < TTOT && cs[id1] <= pos0 + 2) ? id1 + 1 : id1;
    int id3 = (id2 < TTOT && cs[id2] <= pos0 + 3) ? id2 + 1 : id2;
    const float m0 = (pos0     < total) ? 1.f : 0.f;
    const float m1 = (pos0 + 1 < total) ? 1.f : 0.f;
    const float m2 = (pos0 + 2 < total) ? 1.f : 0.f;
    const float m3 = (pos0 + 3 < total) ? 1.f : 0.f;
    const int i0 = min(id0, TTOT - 1), i1 = min(id1, TTOT - 1);
    const int i2 = min(id2, TTOT - 1), i3 = min(id3, TTOT - 1);

    const float* Xb = X + (size_t)b * HHD * TTOT;
    float* Ab = aligned + (size_t)b * HHD * MAXL;
#pragma unroll 8
    for (int hh = 0; hh < 48; ++hh) {
        const int h = ht * 48 + hh;
        const float* xr = Xb + (size_t)h * TTOT;
        float4 v;
        v.x = xr[i0] * m0; v.y = xr[i1] * m1;
        v.z = xr[i2] * m2; v.w = xr[i3] * m3;
        *(float4*)&Ab[(size_t)h * MAXL + pos0] = v;
    }
}

// ---------------------------------------------------------------------------
extern "C" void kernel_launch(void* const* d_in, const int* in_sizes, int n_in,
                              void* d_out, int out_size, void* d_ws, size_t ws_size,
                              hipStream_t stream) {
    const float* x   = (const float*)d_in[0];
    const float* W1  = (const float*)d_in[1];
    const float* b1  = (const float*)d_in[2];
    const float* g1  = (const float*)d_in[3];
    const float* be1 = (const float*)d_in[4];
    const float* W2  = (const float*)d_in[5];
    const float* b2  = (const float*)d_in[6];
    const float* g2  = (const float*)d_in[7];
    const float* be2 = (const float*)d_in[8];
    const float* Wl  = (const float*)d_in[9];
    const float* bl  = (const float*)d_in[10];

    float* out     = (float*)d_out;
    float* durOut  = out;                        // [B*T]
    float* aligned = out + (size_t)BB * TTOT;    // [B*H*MAXL]
    float* h_raw   = aligned;                    // alias; gather runs last

    char* ws = (char*)d_ws;
    const size_t wqB = (size_t)442368 * sizeof(_Float16);
    const size_t xtB = (size_t)BB * TTOT * HHD * sizeof(_Float16);
    _Float16* Wq1h = (_Float16*)(ws);
    _Float16* Wq1l = (_Float16*)(ws + wqB);
    _Float16* Wq2h = (_Float16*)(ws + 2 * wqB);
    _Float16* Wq2l = (_Float16*)(ws + 3 * wqB);
    _Float16* Xt1  = (_Float16*)(ws + 4 * wqB);          // reused as H1t1
    _Float16* Xt2  = (_Float16*)(ws + 4 * wqB + xtB);    // reused as H1t2
    float*    zb   = (float*)   (ws + 4 * wqB + 2 * xtB);
    int*      cum  = (int*)     (ws + 4 * wqB + 2 * xtB + (size_t)BB * TTOT * 4);

    prep_w_kernel<<<dim3(1728, 2), 256, 0, stream>>>(W1, W2, Wq1h, Wq1l, Wq2h, Wq2l);
    prep_x_kernel<<<dim3(6, 16, 32), 256, 0, stream>>>(x, Xt1, Xt2);
    conv_mfma_kernel<<<dim3(4, 8, 32), 256, 0, stream>>>(Xt1, Xt2, Wq1h, Wq1l, b1, h_raw);
    ln_split_kernel<<<8192, 256, 0, stream>>>(h_raw, g1, be1, Xt1, Xt2);
    conv_mfma_kernel<<<dim3(4, 8, 32), 256, 0, stream>>>(Xt1, Xt2, Wq2h, Wq2l, b2, h_raw);
    ln_proj_kernel<<<8192, 256, 0, stream>>>(h_raw, g2, be2, Wl, bl, zb);
    dur_scan_kernel<<<BB, 256, 0, stream>>>(zb, durOut, cum);
    gather_kernel<<<dim3(4, 8, BB), 256, 0, stream>>>(x, cum, aligned);
}